// Round 1
// baseline (1806.522 us; speedup 1.0000x reference)
//
#include <hip/hip_runtime.h>

#define B_ROWS 2048
#define N_GLB  65536
#define DDIM   128
#define INV_T  (1.0f/0.07f)
#define NSPLIT 16
#define NC_CHUNK (N_GLB/NSPLIT)   // 4096
#define TR 64
#define GT 64
#define NTILES (NC_CHUNK/GT)      // 64
#define SPITCH 132                // shorts per LDS row (128 + 4 pad)
#define TOPK 10
#define NEG_BIG (-1.0e30f)

__device__ __forceinline__ unsigned short f2bf(float x) {
  unsigned int u = __float_as_uint(x);
  u += 0x7fffu + ((u >> 16) & 1u);   // round-to-nearest-even
  return (unsigned short)(u >> 16);
}

// one wave per row: inv-norm for f (with 1/T folded) and g
__global__ void norm_kernel(const float* __restrict__ f,
                            const float* __restrict__ g,
                            float* __restrict__ inv_f,
                            float* __restrict__ inv_g) {
  int w = (blockIdx.x * blockDim.x + threadIdx.x) >> 6;
  int lane = threadIdx.x & 63;
  if (w >= B_ROWS + N_GLB) return;
  const float* src = (w < B_ROWS) ? (f + (size_t)w * DDIM)
                                  : (g + (size_t)(w - B_ROWS) * DDIM);
  float2 v = ((const float2*)src)[lane];
  float ss = v.x * v.x + v.y * v.y;
  #pragma unroll
  for (int o = 32; o; o >>= 1) ss += __shfl_down(ss, o);
  if (lane == 0) {
    float inv = 1.0f / fmaxf(sqrtf(ss), 1e-12f);
    if (w < B_ROWS) inv_f[w] = inv * INV_T;
    else            inv_g[w - B_ROWS] = inv;
  }
}

__global__ __launch_bounds__(256) void sim_kernel(
    const float* __restrict__ f, const int* __restrict__ fclust,
    const float* __restrict__ g, const int* __restrict__ gclust,
    const float* __restrict__ inv_f, const float* __restrict__ inv_g,
    float* __restrict__ p_se, float* __restrict__ p_S, float* __restrict__ p_C,
    float* __restrict__ p_tv, int* __restrict__ p_ti)
{
  __shared__ unsigned short fs[TR][SPITCH];
  __shared__ unsigned short gs[GT][SPITCH];
  __shared__ int   gcs[GT];
  __shared__ int   rcs[TR];
  __shared__ float topv[TR][TOPK];
  __shared__ int   topi[TR][TOPK];
  __shared__ float topmin[TR];
  __shared__ float red[TR][16];

  const int t    = threadIdx.x;
  const int tx   = t & 15;          // g-column group
  const int ty   = t >> 4;          // f-row group (rows wave-private: wave w owns r in [16w,16w+16))
  const int lane = t & 63;
  const int r0   = blockIdx.x * TR;
  const int j0   = blockIdx.y * NC_CHUNK;
  const int xg   = tx >> 2;         // LDS swizzle key for this thread's g rows (j>>4)

  for (int i = t; i < TR * TOPK; i += 256) {
    (&topv[0][0])[i] = NEG_BIG;
    (&topi[0][0])[i] = 0;
  }
  for (int i = t; i < TR; i += 256) {
    topmin[i] = NEG_BIG;
    rcs[i] = fclust[r0 + i];
  }

  // stage f tile once (bf16, scaled by inv_f = 1/(max(||f||,eps)*T))
  for (int q = t; q < TR * (DDIM / 4); q += 256) {
    int r = q >> 5, d4 = q & 31;
    float4 v = ((const float4*)(f + (size_t)(r0 + r) * DDIM))[d4];
    float s = inv_f[r0 + r];
    unsigned lo = (unsigned)f2bf(v.x * s) | ((unsigned)f2bf(v.y * s) << 16);
    unsigned hi = (unsigned)f2bf(v.z * s) | ((unsigned)f2bf(v.w * s) << 16);
    *(uint2*)&fs[r][d4 * 4] = make_uint2(lo, hi);
  }

  float sumexp[4] = {0.f, 0.f, 0.f, 0.f};
  float Ssum[4]   = {0.f, 0.f, 0.f, 0.f};
  float Ccnt[4]   = {0.f, 0.f, 0.f, 0.f};

  for (int tile = 0; tile < NTILES; ++tile) {
    const int jb = j0 + tile * GT;
    __syncthreads();   // protect gs/gcs from previous tile's readers
    for (int q = t; q < GT * (DDIM / 4); q += 256) {
      int j = q >> 5, d4 = q & 31;
      float4 v = ((const float4*)(g + (size_t)(jb + j) * DDIM))[d4];
      float s = inv_g[jb + j];
      unsigned lo = (unsigned)f2bf(v.x * s) | ((unsigned)f2bf(v.y * s) << 16);
      unsigned hi = (unsigned)f2bf(v.z * s) | ((unsigned)f2bf(v.w * s) << 16);
      int d4p = d4 ^ ((j >> 4) & 3);   // XOR swizzle: breaks 4-way read conflict
      *(uint2*)&gs[j][d4p * 4] = make_uint2(lo, hi);
    }
    if (t < GT) gcs[t] = gclust[jb + t];
    __syncthreads();

    float acc[4][4];
    #pragma unroll
    for (int e = 0; e < 4; ++e)
      #pragma unroll
      for (int k = 0; k < 4; ++k) acc[e][k] = 0.f;

    #pragma unroll 2
    for (int d4 = 0; d4 < 32; ++d4) {
      const int dpg = (d4 ^ xg) * 4;
      uint2 fw[4], gw[4];
      #pragma unroll
      for (int e = 0; e < 4; ++e) fw[e] = *(const uint2*)&fs[ty * 4 + e][d4 * 4];
      #pragma unroll
      for (int k = 0; k < 4; ++k) gw[k] = *(const uint2*)&gs[tx * 4 + k][dpg];
      float fv[4][4], gv[4][4];
      #pragma unroll
      for (int e = 0; e < 4; ++e) {
        fv[e][0] = __uint_as_float(fw[e].x << 16);
        fv[e][1] = __uint_as_float(fw[e].x & 0xffff0000u);
        fv[e][2] = __uint_as_float(fw[e].y << 16);
        fv[e][3] = __uint_as_float(fw[e].y & 0xffff0000u);
      }
      #pragma unroll
      for (int k = 0; k < 4; ++k) {
        gv[k][0] = __uint_as_float(gw[k].x << 16);
        gv[k][1] = __uint_as_float(gw[k].x & 0xffff0000u);
        gv[k][2] = __uint_as_float(gw[k].y << 16);
        gv[k][3] = __uint_as_float(gw[k].y & 0xffff0000u);
      }
      #pragma unroll
      for (int e = 0; e < 4; ++e)
        #pragma unroll
        for (int k = 0; k < 4; ++k)
          acc[e][k] += fv[e][0] * gv[k][0] + fv[e][1] * gv[k][1]
                     + fv[e][2] * gv[k][2] + fv[e][3] * gv[k][3];
    }

    // fused per-sim epilogue: sum-exp (no max needed: |sim| <= 14.3), cluster sums
    #pragma unroll
    for (int e = 0; e < 4; ++e) {
      const int r = ty * 4 + e;
      const int rc = rcs[r];
      float se = 0.f;
      #pragma unroll
      for (int k = 0; k < 4; ++k) {
        float sim = acc[e][k];
        se += __expf(sim);
        if (gcs[tx * 4 + k] == rc) { Ssum[e] += sim; Ccnt[e] += 1.f; }
      }
      sumexp[e] += se;
    }

    // top-10 candidates: ballot-serialized within the wave (rows are wave-private)
    #pragma unroll
    for (int s = 0; s < 16; ++s) {
      const int e = s >> 2, k = s & 3;
      const int r = ty * 4 + e;
      float sim = acc[e][k];
      bool cand = sim > ((volatile float*)topmin)[r];
      unsigned long long m = __ballot(cand);
      while (m) {
        int leader = __ffsll(m) - 1;
        m &= (m - 1);
        if (lane == leader) {
          volatile float* vv = (volatile float*)topv[r];
          int ms = 0; float mn = vv[0];
          #pragma unroll
          for (int i = 1; i < TOPK; ++i) { float x = vv[i]; if (x < mn) { mn = x; ms = i; } }
          if (sim > mn) {
            vv[ms] = sim;
            ((volatile int*)topi[r])[ms] = jb + tx * 4 + k;
            float nm = vv[0];
            #pragma unroll
            for (int i = 1; i < TOPK; ++i) nm = fminf(nm, vv[i]);
            ((volatile float*)topmin)[r] = nm;
          }
        }
      }
    }
  }

  // cross-thread reductions (16 tx-threads share each row)
  __syncthreads();
  #pragma unroll
  for (int e = 0; e < 4; ++e) red[ty * 4 + e][tx] = sumexp[e];
  __syncthreads();
  if (t < TR) {
    float s = 0.f;
    for (int i = 0; i < 16; ++i) s += red[t][i];
    p_se[(size_t)(r0 + t) * NSPLIT + blockIdx.y] = s;
  }
  __syncthreads();
  #pragma unroll
  for (int e = 0; e < 4; ++e) red[ty * 4 + e][tx] = Ssum[e];
  __syncthreads();
  if (t < TR) {
    float s = 0.f;
    for (int i = 0; i < 16; ++i) s += red[t][i];
    p_S[(size_t)(r0 + t) * NSPLIT + blockIdx.y] = s;
  }
  __syncthreads();
  #pragma unroll
  for (int e = 0; e < 4; ++e) red[ty * 4 + e][tx] = Ccnt[e];
  __syncthreads();
  if (t < TR) {
    float s = 0.f;
    for (int i = 0; i < 16; ++i) s += red[t][i];
    p_C[(size_t)(r0 + t) * NSPLIT + blockIdx.y] = s;
  }

  for (int i = t; i < TR * TOPK; i += 256) {
    int r = i / TOPK, sl = i % TOPK;
    size_t o = ((size_t)(r0 + r) * NSPLIT + blockIdx.y) * TOPK + sl;
    p_tv[o] = topv[r][sl];
    p_ti[o] = topi[r][sl];
  }
}

// per-row merge of NSPLIT partials
__global__ void merge_kernel(const int* __restrict__ fclust,
                             const int* __restrict__ gclust,
                             const float* __restrict__ p_se,
                             const float* __restrict__ p_S,
                             const float* __restrict__ p_C,
                             const float* __restrict__ p_tv,
                             const int* __restrict__ p_ti,
                             float* __restrict__ rowv) {
  int r = blockIdx.x * blockDim.x + threadIdx.x;
  if (r >= B_ROWS) return;
  float se = 0.f, S = 0.f, C = 0.f;
  for (int c = 0; c < NSPLIT; ++c) {
    se += p_se[(size_t)r * NSPLIT + c];
    S  += p_S [(size_t)r * NSPLIT + c];
    C  += p_C [(size_t)r * NSPLIT + c];
  }
  float tv[TOPK]; int ti[TOPK];
  #pragma unroll
  for (int i = 0; i < TOPK; ++i) { tv[i] = NEG_BIG; ti[i] = 0; }
  for (int c = 0; c < NSPLIT; ++c) {
    for (int s = 0; s < TOPK; ++s) {
      size_t o = ((size_t)r * NSPLIT + c) * TOPK + s;
      float v = p_tv[o];
      int   ix = p_ti[o];
      int ms = 0; float mn = tv[0];
      #pragma unroll
      for (int i = 1; i < TOPK; ++i) { if (tv[i] < mn) { mn = tv[i]; ms = i; } }
      if (v > mn) { tv[ms] = v; ti[ms] = ix; }
    }
  }
  int rc = fclust[r];
  #pragma unroll
  for (int i = 0; i < TOPK; ++i) {
    if (gclust[ti[i]] != rc) { S += tv[i]; C += 1.f; }  // cluster-matched knn already counted
  }
  float L = logf(se + 1e-12f);
  rowv[r] = (S - C * L) / (C + 1e-12f);
}

__global__ void final_kernel(const float* __restrict__ rowv, float* __restrict__ out) {
  __shared__ float sm[256];
  int t = threadIdx.x;
  float s = 0.f;
  for (int i = t; i < B_ROWS; i += 256) s += rowv[i];
  sm[t] = s;
  __syncthreads();
  for (int o = 128; o; o >>= 1) { if (t < o) sm[t] += sm[t + o]; __syncthreads(); }
  if (t == 0) out[0] = -(sm[0] / (float)B_ROWS);
}

extern "C" void kernel_launch(void* const* d_in, const int* in_sizes, int n_in,
                              void* d_out, int out_size, void* d_ws, size_t ws_size,
                              hipStream_t stream) {
  const float* f  = (const float*)d_in[0];
  const int*   fc = (const int*)  d_in[1];
  const float* g  = (const float*)d_in[2];
  const int*   gc = (const int*)  d_in[3];
  float* out = (float*)d_out;

  float* ws    = (float*)d_ws;
  float* inv_f = ws;                                   // 2048
  float* inv_g = inv_f + B_ROWS;                       // 65536
  float* p_se  = inv_g + N_GLB;                        // 2048*16
  float* p_S   = p_se + (size_t)B_ROWS * NSPLIT;
  float* p_C   = p_S  + (size_t)B_ROWS * NSPLIT;
  float* p_tv  = p_C  + (size_t)B_ROWS * NSPLIT;       // 2048*16*10
  int*   p_ti  = (int*)(p_tv + (size_t)B_ROWS * NSPLIT * TOPK);
  float* rowv  = (float*)(p_ti + (size_t)B_ROWS * NSPLIT * TOPK);
  // total ws use: ~3.3 MB

  int nwaves = B_ROWS + N_GLB;
  norm_kernel<<<nwaves / 4, 256, 0, stream>>>(f, g, inv_f, inv_g);

  dim3 grid(B_ROWS / TR, NSPLIT);
  sim_kernel<<<grid, 256, 0, stream>>>(f, fc, g, gc, inv_f, inv_g,
                                       p_se, p_S, p_C, p_tv, p_ti);

  merge_kernel<<<(B_ROWS + 255) / 256, 256, 0, stream>>>(fc, gc, p_se, p_S, p_C,
                                                          p_tv, p_ti, rowv);
  final_kernel<<<1, 256, 0, stream>>>(rowv, out);
}

// Round 2
// 345.723 us; speedup vs baseline: 5.2253x; 5.2253x over previous
//
#include <hip/hip_runtime.h>

#define B_ROWS 2048
#define N_GLB  65536
#define DDIM   128
#define INV_T  (1.0f/0.07f)
#define NSPLIT 16
#define NC_CHUNK 4096          // g cols per chunk
#define NTILES 64              // 64-row g tiles per chunk
#define TOPK 10
#define TILE_B 16384           // 64 rows * 128 bf16 * 2B

typedef __attribute__((ext_vector_type(8))) short sh8;     // 8 bf16 = 4 VGPRs (MFMA A/B frag)
typedef __attribute__((ext_vector_type(4))) float f32x4;   // MFMA C/D frag

__device__ __forceinline__ unsigned f2bf(float x) {
  unsigned u = __float_as_uint(x);
  u += 0x7fffu + ((u >> 16) & 1u);   // RNE
  return u >> 16;
}

// One wave per row: L2 norm, scale, bf16-convert, write to ws in swizzled tile layout.
// Tile layout: tile = row/64 (16384 B each); within tile: row r (0..63), byte b:
//   ws_off = tile*16384 + r*256 + (b ^ ((r&7)<<4))
// Linear LDS staging of a tile then reproduces this layout; ds_read applies same XOR.
__global__ void prep_kernel(const float* __restrict__ f, const float* __restrict__ g,
                            char* __restrict__ wsf, char* __restrict__ wsg) {
  int w = (blockIdx.x * blockDim.x + threadIdx.x) >> 6;
  int lane = threadIdx.x & 63;
  if (w >= B_ROWS + N_GLB) return;
  bool isf = (w < B_ROWS);
  int r = isf ? w : (w - B_ROWS);
  const float* src = (isf ? f : g) + (size_t)r * DDIM;
  float2 v = ((const float2*)src)[lane];
  float ss = v.x * v.x + v.y * v.y;
  #pragma unroll
  for (int m = 32; m; m >>= 1) ss += __shfl_xor(ss, m);
  float inv = 1.0f / fmaxf(sqrtf(ss), 1e-12f);
  if (isf) inv *= INV_T;                       // fold 1/T into f
  unsigned pk = f2bf(v.x * inv) | (f2bf(v.y * inv) << 16);
  char* base = isf ? wsf : wsg;
  int rit = r & 63;
  size_t off = (size_t)(r >> 6) * TILE_B + (size_t)rit * 256
             + (size_t)((4 * lane) ^ ((rit & 7) << 4));
  *(unsigned*)(base + off) = pk;
}

__global__ __launch_bounds__(256, 2) void sim_kernel(
    const char* __restrict__ wsf, const char* __restrict__ wsg,
    const int* __restrict__ fclust, const int* __restrict__ gclust,
    float* __restrict__ p_se, float* __restrict__ p_S, float* __restrict__ p_C,
    float* __restrict__ p_tv)
{
  __shared__ char smem[49152];           // [0,16K) f tile; [16K,32K)+[32K,48K) g dbuf
  char* fbuf  = smem;
  char* gbuf0 = smem + 16384;
  char* gbuf1 = smem + 32768;

  const int t = threadIdx.x;
  const int lane = t & 63, w = t >> 6;   // wave w owns f-rows [w*16, w*16+16)
  const int l15 = lane & 15, lhi = lane >> 4;
  const int key = (l15 & 7) << 4;        // read-side XOR swizzle key (row&7)<<4
  const int r0 = blockIdx.x * 64;
  const int chunk = blockIdx.y;
  const char* gsrc = wsg + (size_t)chunk * NTILES * TILE_B;

  // stage f tile (reg-staged linear copy; ws already swizzled)
  {
    const char* fs = wsf + (size_t)blockIdx.x * TILE_B;
    uint4 rf[4];
    #pragma unroll
    for (int i = 0; i < 4; ++i) rf[i] = *(const uint4*)(fs + i * 4096 + t * 16);
    #pragma unroll
    for (int i = 0; i < 4; ++i) *(uint4*)(fbuf + i * 4096 + t * 16) = rf[i];
  }
  // stage g tile 0
  uint4 rg[4];
  #pragma unroll
  for (int i = 0; i < 4; ++i) rg[i] = *(const uint4*)(gsrc + i * 4096 + t * 16);
  #pragma unroll
  for (int i = 0; i < 4; ++i) *(uint4*)(gbuf0 + i * 4096 + t * 16) = rg[i];

  __syncthreads();

  // A-frags are loop-invariant: hoist. A[i][k]: i=lane&15, k=(lane>>4)*8+b
  sh8 afr[4];
  #pragma unroll
  for (int s = 0; s < 4; ++s)
    afr[s] = *(const sh8*)(fbuf + (w * 16 + l15) * 256 + ((s * 64 + lhi * 16) ^ key));

  int rc[4];   // row clusters for this lane's 4 output rows (reg q): row = w*16+lhi*4+q
  #pragma unroll
  for (int q = 0; q < 4; ++q) rc[q] = fclust[r0 + w * 16 + lhi * 4 + q];

  float se[4] = {0, 0, 0, 0}, Ss[4] = {0, 0, 0, 0}, Cc[4] = {0, 0, 0, 0};
  // per-lane per-row top-10, value-packed: bits = (f32(sim) & ~0xFFF) | col12
  float tk[4][TOPK], mn[4];
  #pragma unroll
  for (int q = 0; q < 4; ++q) {
    #pragma unroll
    for (int i = 0; i < TOPK; ++i) tk[q][i] = -1.0e30f - (float)i * 1.0e26f; // distinct
    float m0 = tk[q][0];
    #pragma unroll
    for (int i = 1; i < TOPK; ++i) m0 = fminf(m0, tk[q][i]);
    mn[q] = m0;
  }

  int cur = 0;
  for (int tile = 0; tile < NTILES; ++tile) {
    // T14 async split: issue next-tile global loads before compute
    if (tile + 1 < NTILES) {
      const char* gs = gsrc + (size_t)(tile + 1) * TILE_B;
      #pragma unroll
      for (int i = 0; i < 4; ++i) rg[i] = *(const uint4*)(gs + i * 4096 + t * 16);
    }
    __syncthreads();   // prev iter's ds_writes to buf[cur] now visible
    const char* gb = cur ? gbuf1 : gbuf0;

    // g clusters for this lane's 4 columns (issued early, hide under MFMA)
    int gcn[4];
    const int colb = chunk * NC_CHUNK + tile * 64;
    #pragma unroll
    for (int n = 0; n < 4; ++n) gcn[n] = gclust[colb + n * 16 + l15];

    // 16 MFMAs: D[i][j] = sum_k fn[i][k]*gn[j][k]; B[k][j]: j=lane&15, k=(lane>>4)*8+b
    f32x4 acc[4];
    #pragma unroll
    for (int n = 0; n < 4; ++n) {
      f32x4 z = {0.f, 0.f, 0.f, 0.f};
      acc[n] = z;
      #pragma unroll
      for (int s = 0; s < 4; ++s) {
        sh8 bfr = *(const sh8*)(gb + (n * 16 + l15) * 256 + ((s * 64 + lhi * 16) ^ key));
        acc[n] = __builtin_amdgcn_mfma_f32_16x16x32_bf16(afr[s], bfr, acc[n], 0, 0, 0);
      }
    }

    // fused epilogue: C/D layout col=lane&15, row=(lane>>4)*4+reg
    #pragma unroll
    for (int n = 0; n < 4; ++n) {
      const int col12 = tile * 64 + n * 16 + l15;   // col id within chunk (12 bits)
      #pragma unroll
      for (int q = 0; q < 4; ++q) {
        float sim = acc[n][q];
        se[q] += __expf(sim);                       // no max-sub needed: |sim| <= ~15
        bool cm = (gcn[n] == rc[q]);
        Ss[q] += cm ? sim : 0.0f;
        Cc[q] += cm ? 1.0f : 0.0f;
        float pv = __uint_as_float((__float_as_uint(sim) & 0xFFFFF000u) | (unsigned)col12);
        if (pv > mn[q]) {                           // static-indexed replace-min insert
          float m = mn[q];
          #pragma unroll
          for (int i = 0; i < TOPK; ++i) tk[q][i] = (tk[q][i] == m) ? pv : tk[q][i];
          float nm = tk[q][0];
          #pragma unroll
          for (int i = 1; i < TOPK; ++i) nm = fminf(nm, tk[q][i]);
          mn[q] = nm;
        }
      }
    }

    // write prefetched tile into the other buffer
    if (tile + 1 < NTILES) {
      char* gw = cur ? gbuf0 : gbuf1;
      #pragma unroll
      for (int i = 0; i < 4; ++i) *(uint4*)(gw + i * 4096 + t * 16) = rg[i];
      cur ^= 1;
    }
  }

  // cross-lane sums: 16 lanes (l15) share each output row; xor masks 8,4,2,1 stay in-group
  #pragma unroll
  for (int q = 0; q < 4; ++q) {
    float a = se[q], b = Ss[q], c = Cc[q];
    #pragma unroll
    for (int m = 8; m; m >>= 1) {
      a += __shfl_xor(a, m);
      b += __shfl_xor(b, m);
      c += __shfl_xor(c, m);
    }
    if (l15 == 0) {
      int rl = w * 16 + lhi * 4 + q;
      size_t o = (size_t)(r0 + rl) * NSPLIT + chunk;
      p_se[o] = a; p_S[o] = b; p_C[o] = c;
    }
  }

  // block-level top-k merge: dump 16 lanes x 10 per row to LDS overlay, select top-10
  __syncthreads();                     // all waves done reading g tiles
  float* mrg = (float*)smem;           // 64 rows * 160 floats = 40 KB (< 48 KB)
  #pragma unroll
  for (int q = 0; q < 4; ++q) {
    int rl = w * 16 + lhi * 4 + q;
    #pragma unroll
    for (int i = 0; i < TOPK; ++i) mrg[(rl * 16 + l15) * TOPK + i] = tk[q][i];
  }
  __syncthreads();
  if ((t & 3) == 0) {                  // 64 selector threads spread across all 4 waves
    int rl = t >> 2;
    float bv[TOPK];
    #pragma unroll
    for (int i = 0; i < TOPK; ++i) bv[i] = -1.0e30f - (float)i * 1.0e26f;
    float m = bv[0];
    #pragma unroll
    for (int i = 1; i < TOPK; ++i) m = fminf(m, bv[i]);
    for (int i = 0; i < 160; ++i) {
      float x = mrg[rl * 160 + i];
      if (x > m) {
        bool done = false;
        #pragma unroll
        for (int j = 0; j < TOPK; ++j) {
          bool h = (!done) && (bv[j] == m);
          bv[j] = h ? x : bv[j];
          done = done || h;
        }
        m = bv[0];
        #pragma unroll
        for (int j = 1; j < TOPK; ++j) m = fminf(m, bv[j]);
      }
    }
    size_t o = ((size_t)(r0 + rl) * NSPLIT + chunk) * TOPK;
    #pragma unroll
    for (int i = 0; i < TOPK; ++i) p_tv[o + i] = bv[i];
  }
}

// per-row merge of NSPLIT chunk partials
__global__ void merge_kernel(const int* __restrict__ fclust, const int* __restrict__ gclust,
                             const float* __restrict__ p_se, const float* __restrict__ p_S,
                             const float* __restrict__ p_C, const float* __restrict__ p_tv,
                             float* __restrict__ rowv)
{
  int r = blockIdx.x * blockDim.x + threadIdx.x;
  if (r >= B_ROWS) return;
  float se = 0.f, S = 0.f, C = 0.f;
  for (int c = 0; c < NSPLIT; ++c) {
    se += p_se[(size_t)r * NSPLIT + c];
    S  += p_S [(size_t)r * NSPLIT + c];
    C  += p_C [(size_t)r * NSPLIT + c];
  }
  float bv[TOPK]; int bc[TOPK];
  #pragma unroll
  for (int i = 0; i < TOPK; ++i) { bv[i] = -1.0e30f - (float)i * 1.0e26f; bc[i] = 0; }
  float m = bv[0];
  #pragma unroll
  for (int i = 1; i < TOPK; ++i) m = fminf(m, bv[i]);
  for (int c = 0; c < NSPLIT; ++c) {
    #pragma unroll
    for (int i = 0; i < TOPK; ++i) {
      float x = p_tv[((size_t)r * NSPLIT + c) * TOPK + i];
      if (x > m) {
        bool done = false;            // packed values can collide across chunks
        #pragma unroll
        for (int j = 0; j < TOPK; ++j) {
          bool h = (!done) && (bv[j] == m);
          bc[j] = h ? c : bc[j];
          bv[j] = h ? x : bv[j];
          done = done || h;
        }
        m = bv[0];
        #pragma unroll
        for (int j = 1; j < TOPK; ++j) m = fminf(m, bv[j]);
      }
    }
  }
  int rcl = fclust[r];
  #pragma unroll
  for (int i = 0; i < TOPK; ++i) {
    unsigned bits = __float_as_uint(bv[i]);
    int gi = bc[i] * NC_CHUNK + (int)(bits & 0xFFFu);
    float val = __uint_as_float(bits & 0xFFFFF000u);
    if (gclust[gi] != rcl) { S += val; C += 1.f; }   // knn entries not already in cluster
  }
  float L = logf(se + 1e-12f);
  rowv[r] = (S - C * L) / (C + 1e-12f);
}

__global__ void final_kernel(const float* __restrict__ rowv, float* __restrict__ out) {
  __shared__ float sm[256];
  int t = threadIdx.x;
  float s = 0.f;
  for (int i = t; i < B_ROWS; i += 256) s += rowv[i];
  sm[t] = s;
  __syncthreads();
  for (int o = 128; o; o >>= 1) { if (t < o) sm[t] += sm[t + o]; __syncthreads(); }
  if (t == 0) out[0] = -(sm[0] / (float)B_ROWS);
}

extern "C" void kernel_launch(void* const* d_in, const int* in_sizes, int n_in,
                              void* d_out, int out_size, void* d_ws, size_t ws_size,
                              hipStream_t stream) {
  const float* f  = (const float*)d_in[0];
  const int*   fc = (const int*)  d_in[1];
  const float* g  = (const float*)d_in[2];
  const int*   gc = (const int*)  d_in[3];
  float* out = (float*)d_out;

  char* wsf = (char*)d_ws;                              // 2048*128*2   = 512 KB
  char* wsg = wsf + (size_t)B_ROWS * DDIM * 2;          // 65536*128*2  = 16 MB
  float* p_se = (float*)(wsg + (size_t)N_GLB * DDIM * 2);
  float* p_S  = p_se + (size_t)B_ROWS * NSPLIT;
  float* p_C  = p_S  + (size_t)B_ROWS * NSPLIT;
  float* p_tv = p_C  + (size_t)B_ROWS * NSPLIT;         // 2048*16*10 f32 = 1.25 MB
  float* rowv = p_tv + (size_t)B_ROWS * NSPLIT * TOPK;
  // total ws: ~18.6 MB

  prep_kernel<<<(B_ROWS + N_GLB) / 4, 256, 0, stream>>>(f, g, wsf, wsg);

  dim3 grid(B_ROWS / 64, NSPLIT);   // 32 x 16 = 512 blocks (2/CU, 8 waves/CU)
  sim_kernel<<<grid, 256, 0, stream>>>(wsf, wsg, fc, gc, p_se, p_S, p_C, p_tv);

  merge_kernel<<<(B_ROWS + 255) / 256, 256, 0, stream>>>(fc, gc, p_se, p_S, p_C, p_tv, rowv);
  final_kernel<<<1, 256, 0, stream>>>(rowv, out);
}

// Round 3
// 293.975 us; speedup vs baseline: 6.1452x; 1.1760x over previous
//
#include <hip/hip_runtime.h>

#define B_ROWS 2048
#define N_GLB  65536
#define DDIM   128
#define NCLUST 100
#define INV_T  (1.0f/0.07f)
#define LOG2E  1.4426950408889634f
#define LN2    0.6931471805599453f
#define NSPLIT 16
#define CHUNK_COLS (N_GLB/NSPLIT)   // 4096
#define ITERS (CHUNK_COLS/64)       // 64 iters, 64 cols per block-iter (16/wave)
#define TOPK 10
#define CAP  256
#define TAU_L2E (3.7881f*LOG2E)     // 3.0 sigma threshold, in log2e units
#define CSC    65536.0f             // csum fixed-point scale 2^16
#define INV_CSC (1.0f/65536.0f)

typedef __attribute__((ext_vector_type(8))) short sh8;
typedef __attribute__((ext_vector_type(4))) float f32x4;
typedef unsigned long long u64;

__device__ __forceinline__ unsigned f2bf(float x) {
  unsigned u = __float_as_uint(x);
  u += 0x7fffu + ((u >> 16) & 1u);   // RNE
  return u >> 16;
}
__device__ __forceinline__ unsigned fmono(float v) {  // order-preserving f32->u32
  unsigned u = __float_as_uint(v);
  return ((int)u < 0) ? ~u : (u | 0x80000000u);
}
__device__ __forceinline__ float fmono_inv(unsigned m) {
  unsigned u = (m & 0x80000000u) ? (m & 0x7FFFFFFFu) : ~m;
  return __uint_as_float(u);
}
__device__ __forceinline__ u64 mkkey(float val, int col) {
  return ((u64)fmono(val) << 32) | (unsigned)(~(unsigned)col);
}
__device__ __forceinline__ u64 umax64(u64 a, u64 b) { return a > b ? a : b; }

// ---- prep: normalize, bf16-convert, write fragment-direct layout ----
// layout: row r, dim k: byte = (r>>4)*4096 + ((k>>3))*256 + (r&15)*16 + (k&7)*2
// so a wave's 4 loads per 16-row group (addr = R*4096 + s*1024 + lane*16) are
// exactly the mfma_f32_16x16x32_bf16 A/B fragments (j=lane&15, k=(lane>>4)*8+b+32s).
__global__ void prep_kernel(const float* __restrict__ f, const float* __restrict__ g,
                            char* __restrict__ wsf2, char* __restrict__ wsg2,
                            float* __restrict__ inv_fT, float* __restrict__ inv_g) {
  int row = (blockIdx.x * blockDim.x + threadIdx.x) >> 6;
  int lane = threadIdx.x & 63;
  if (row >= B_ROWS + N_GLB) return;
  bool isf = row < B_ROWS;
  int rr = isf ? row : row - B_ROWS;
  const float* src = (isf ? f : g) + (size_t)rr * DDIM;
  float2 v = ((const float2*)src)[lane];               // dims 2*lane, 2*lane+1
  float ss = v.x * v.x + v.y * v.y;
  #pragma unroll
  for (int m = 32; m; m >>= 1) ss += __shfl_xor(ss, m);
  float inv = 1.0f / fmaxf(sqrtf(ss), 1e-12f);
  if (lane == 0) { if (isf) inv_fT[rr] = inv * INV_T; else inv_g[rr] = inv; }
  float sc = isf ? inv * (INV_T * LOG2E) : inv;        // fold 1/T and log2e into f
  unsigned pk = f2bf(v.x * sc) | (f2bf(v.y * sc) << 16);
  char* base = isf ? wsf2 : wsg2;
  *(unsigned*)(base + (size_t)(rr >> 4) * 4096 + (size_t)(lane >> 2) * 256
               + (size_t)(rr & 15) * 16 + (size_t)(lane & 3) * 4) = pk;
}

// ---- cluster sums: csum[c][d] = sum of normalized g rows in cluster c (fixed-point) ----
__global__ __launch_bounds__(128) void csum_kernel(const float* __restrict__ g,
                                                   const int* __restrict__ gclust,
                                                   const float* __restrict__ inv_g,
                                                   int* __restrict__ csum_i32,
                                                   int* __restrict__ hist) {
  __shared__ float cs[NCLUST * DDIM];   // 51.2 KB
  __shared__ int lcnt[NCLUST];
  int t = threadIdx.x;                  // 128 threads; thread t owns dim t
  for (int i = t; i < NCLUST * DDIM; i += 128) cs[i] = 0.f;
  if (t < NCLUST) lcnt[t] = 0;
  __syncthreads();
  int j0 = blockIdx.x * 512;
  for (int j = 0; j < 512; ++j) {
    int r = j0 + j;
    int c = gclust[r];                  // uniform per iteration
    cs[c * DDIM + t] += g[(size_t)r * DDIM + t] * inv_g[r];  // only thread t touches dim t -> race-free
    if (t == 0) lcnt[c]++;
  }
  __syncthreads();
  for (int i = t; i < NCLUST * DDIM; i += 128) {
    float x = cs[i];
    if (x != 0.f) atomicAdd(&csum_i32[i], (int)rintf(x * CSC));  // int atomics: deterministic
  }
  if (t < NCLUST && lcnt[t]) atomicAdd(&hist[t], lcnt[t]);
}

// ---- sim: no-LDS MFMA GEMM + fused exp-sum + threshold push ----
#define PUSHQ(av, mm, q)                                                        \
  if ((av) > TAU_L2E) {                                                         \
    int rw = r0 + (mm) * 16 + lhi * 4 + (q);                                    \
    int slot = atomicAdd(&cnt[rw], 1);                                          \
    if (slot < CAP) { lv[rw * CAP + slot] = (av) * LN2; li[rw * CAP + slot] = colv; } \
  }

#define EPI(a, mm)                                                              \
  {                                                                             \
    se[mm].x += exp2f(a.x); se[mm].y += exp2f(a.y);                             \
    se[mm].z += exp2f(a.z); se[mm].w += exp2f(a.w);                             \
    float mx = fmaxf(fmaxf(a.x, a.y), fmaxf(a.z, a.w));                         \
    if (mx > TAU_L2E) { PUSHQ(a.x, mm, 0) PUSHQ(a.y, mm, 1) PUSHQ(a.z, mm, 2) PUSHQ(a.w, mm, 3) } \
  }

#define LOADB(dst, gptr)                                                        \
  { _Pragma("unroll") for (int s = 0; s < 4; ++s)                               \
      dst[s] = *(const uint4*)((gptr) + s * 1024 + (size_t)lane * 16); }

#define COMPUTE(bb, itv)                                                        \
  {                                                                             \
    f32x4 ac0 = {0,0,0,0}, ac1 = {0,0,0,0}, ac2 = {0,0,0,0}, ac3 = {0,0,0,0};   \
    _Pragma("unroll") for (int s = 0; s < 4; ++s) {                             \
      sh8 bs = __builtin_bit_cast(sh8, bb[s]);                                  \
      ac0 = __builtin_amdgcn_mfma_f32_16x16x32_bf16(afr[0][s], bs, ac0, 0, 0, 0); \
      ac1 = __builtin_amdgcn_mfma_f32_16x16x32_bf16(afr[1][s], bs, ac1, 0, 0, 0); \
      ac2 = __builtin_amdgcn_mfma_f32_16x16x32_bf16(afr[2][s], bs, ac2, 0, 0, 0); \
      ac3 = __builtin_amdgcn_mfma_f32_16x16x32_bf16(afr[3][s], bs, ac3, 0, 0, 0); \
    }                                                                           \
    const int colv = chunk * CHUNK_COLS + (itv) * 64 + w * 16 + l15;            \
    EPI(ac0, 0) EPI(ac1, 1) EPI(ac2, 2) EPI(ac3, 3)                             \
  }

__global__ __launch_bounds__(256, 3) void sim_kernel(
    const char* __restrict__ wsf2, const char* __restrict__ wsg2,
    float* __restrict__ p_se, float* __restrict__ lv, int* __restrict__ li,
    int* __restrict__ cnt) {
  __shared__ float sered[4][64];
  const int t = threadIdx.x, lane = t & 63, w = t >> 6;
  const int l15 = lane & 15, lhi = lane >> 4;
  const int chunk = blockIdx.x;          // 0..15 (chunk%8 -> XCD: chunk L2-resident)
  const int r0 = blockIdx.y * 64;

  // hoist A fragments: 64 f-rows x 128 K in regs (16 x sh8 = 64 VGPR)
  const char* fbase = wsf2 + (size_t)(r0 >> 4) * 4096;
  sh8 afr[4][4];
  #pragma unroll
  for (int m = 0; m < 4; ++m)
    #pragma unroll
    for (int s = 0; s < 4; ++s)
      afr[m][s] = *(const sh8*)(fbase + (size_t)m * 4096 + s * 1024 + (size_t)lane * 16);

  f32x4 z = {0.f, 0.f, 0.f, 0.f};
  f32x4 se[4] = {z, z, z, z};

  // B groups for this wave: R_g = chunk*256 + it*4 + w  (stride 4 groups per iter)
  const char* gb = wsg2 + (size_t)(chunk * 256 + w) * 4096;
  uint4 b0[4], b1[4];
  LOADB(b0, gb)
  for (int it = 0; it < ITERS; it += 2) {
    LOADB(b1, gb + 4 * 4096)             // prefetch odd iter
    COMPUTE(b0, it)
    if (it + 2 < ITERS) { LOADB(b0, gb + 8 * 4096) }  // prefetch next even
    COMPUTE(b1, it + 1)
    gb += 8 * 4096;
  }

  // Sum-exp partials: reduce over l15 (16 lanes share a row), combine 4 waves via LDS
  #pragma unroll
  for (int m = 0; m < 4; ++m)
    #pragma unroll
    for (int q = 0; q < 4; ++q) {
      float s = se[m][q];
      s += __shfl_xor(s, 1); s += __shfl_xor(s, 2);
      s += __shfl_xor(s, 4); s += __shfl_xor(s, 8);
      if (l15 == 0) sered[w][m * 16 + lhi * 4 + q] = s;
    }
  __syncthreads();
  if (t < 64) {
    float s = sered[0][t] + sered[1][t] + sered[2][t] + sered[3][t];
    p_se[(size_t)(r0 + t) * NSPLIT + chunk] = s;
  }
}

// ---- merge: per-row (one wave) se, cluster dot, exact top-10 from candidate list ----
__global__ __launch_bounds__(256) void merge_kernel(
    const float* __restrict__ f, const int* __restrict__ fclust,
    const int* __restrict__ gclust, const float* __restrict__ inv_fT,
    const float* __restrict__ p_se, const int* __restrict__ csum_i32,
    const int* __restrict__ hist, const float* __restrict__ lv,
    const int* __restrict__ li, const int* __restrict__ cnt,
    int* __restrict__ flags, float* __restrict__ rowv) {
  const int lane = threadIdx.x & 63, w = threadIdx.x >> 6;
  const int r = blockIdx.x * 4 + w;

  float sev = (lane < NSPLIT) ? p_se[(size_t)r * NSPLIT + lane] : 0.f;
  sev += __shfl_xor(sev, 8); sev += __shfl_xor(sev, 4);
  sev += __shfl_xor(sev, 2); sev += __shfl_xor(sev, 1);
  sev = __shfl(sev, 0);

  int rc = fclust[r];
  float2 fv = ((const float2*)(f + (size_t)r * DDIM))[lane];
  float sc = inv_fT[r];
  float dt = fv.x * sc * (csum_i32[rc * DDIM + 2 * lane] * INV_CSC)
           + fv.y * sc * (csum_i32[rc * DDIM + 2 * lane + 1] * INV_CSC);
  #pragma unroll
  for (int m = 32; m; m >>= 1) dt += __shfl_xor(dt, m);
  dt = __shfl(dt, 0);

  float Cc = (float)hist[rc];
  int n = cnt[r];
  bool bad = (n < TOPK) || (n > CAP);
  float S10 = 0.f, C10 = 0.f;
  if (!bad) {
    u64 k0 = 0, k1 = 0, k2 = 0, k3 = 0;
    int e = lane;
    if (e < n) k0 = mkkey(lv[(size_t)r * CAP + e], li[(size_t)r * CAP + e]);
    e = lane + 64;
    if (e < n) k1 = mkkey(lv[(size_t)r * CAP + e], li[(size_t)r * CAP + e]);
    e = lane + 128;
    if (e < n) k2 = mkkey(lv[(size_t)r * CAP + e], li[(size_t)r * CAP + e]);
    e = lane + 192;
    if (e < n) k3 = mkkey(lv[(size_t)r * CAP + e], li[(size_t)r * CAP + e]);
    for (int it = 0; it < TOPK; ++it) {
      u64 best = umax64(umax64(k0, k1), umax64(k2, k3));
      #pragma unroll
      for (int m = 32; m; m >>= 1) best = umax64(best, __shfl_xor(best, m));
      float val = fmono_inv((unsigned)(best >> 32));
      int col = (int)(~(unsigned)(best & 0xFFFFFFFFull));
      int gc = gclust[col];
      if (gc != rc) { S10 += val; C10 += 1.f; }
      if (k0 == best) k0 = 0;
      if (k1 == best) k1 = 0;
      if (k2 == best) k2 = 0;
      if (k3 == best) k3 = 0;
    }
  }
  if (lane == 0) {
    flags[r] = bad ? 1 : 0;
    if (!bad) {
      float L = logf(sev + 1e-12f);
      float C = Cc + C10;
      rowv[r] = (dt + S10 - C * L) / (C + 1e-12f);
    }
  }
}

// ---- fallback: exact top-10 by full recompute for flagged rows (normally none) ----
__global__ __launch_bounds__(256) void fallback_kernel(
    const float* __restrict__ f, const int* __restrict__ fclust,
    const int* __restrict__ gclust, const float* __restrict__ inv_fT,
    const float* __restrict__ p_se, const int* __restrict__ csum_i32,
    const int* __restrict__ hist, const char* __restrict__ wsf2,
    const char* __restrict__ wsg2, const int* __restrict__ flags,
    float* __restrict__ rowv) {
  const int lane = threadIdx.x & 63, w = threadIdx.x >> 6;
  const int r = blockIdx.x * 4 + w;
  if (flags[r] == 0) return;

  uint4 fr[16];
  #pragma unroll
  for (int c = 0; c < 16; ++c)
    fr[c] = *(const uint4*)(wsf2 + (size_t)(r >> 4) * 4096 + c * 256 + (size_t)(r & 15) * 16);

  u64 tk[TOPK];
  #pragma unroll
  for (int i = 0; i < TOPK; ++i) tk[i] = 0;

  for (int col = lane; col < N_GLB; col += 64) {
    const char* gp = wsg2 + (size_t)(col >> 4) * 4096 + (size_t)(col & 15) * 16;
    float acc = 0.f;
    #pragma unroll
    for (int c = 0; c < 16; ++c) {
      uint4 gv = *(const uint4*)(gp + c * 256);
      uint4 fc = fr[c];
      #pragma unroll
      for (int p = 0; p < 4; ++p) {
        unsigned fa = (&fc.x)[p], ga = (&gv.x)[p];
        acc += __uint_as_float(fa << 16) * __uint_as_float(ga << 16)
             + __uint_as_float(fa & 0xFFFF0000u) * __uint_as_float(ga & 0xFFFF0000u);
      }
    }
    u64 key = mkkey(acc, col);   // acc in log2e units; monotonic ordering ok
    if (key > tk[0]) {
      u64 cur = key;
      #pragma unroll
      for (int i = 0; i < TOPK - 1; ++i) {
        u64 nxt = tk[i + 1];
        u64 lo = cur < nxt ? cur : nxt;
        u64 hi = cur < nxt ? nxt : cur;
        tk[i] = lo; cur = hi;
      }
      tk[TOPK - 1] = cur;
    }
  }

  int rc = fclust[r];
  float S10 = 0.f, C10 = 0.f;
  for (int it = 0; it < TOPK; ++it) {
    u64 best = tk[TOPK - 1];
    #pragma unroll
    for (int m = 32; m; m >>= 1) best = umax64(best, __shfl_xor(best, m));
    float val = fmono_inv((unsigned)(best >> 32)) * LN2;  // back to natural units
    int col = (int)(~(unsigned)(best & 0xFFFFFFFFull));
    if (gclust[col] != rc) { S10 += val; C10 += 1.f; }
    if (tk[TOPK - 1] == best) {
      #pragma unroll
      for (int i = TOPK - 1; i > 0; --i) tk[i] = tk[i - 1];
      tk[0] = 0;
    }
  }

  float sev = (lane < NSPLIT) ? p_se[(size_t)r * NSPLIT + lane] : 0.f;
  sev += __shfl_xor(sev, 8); sev += __shfl_xor(sev, 4);
  sev += __shfl_xor(sev, 2); sev += __shfl_xor(sev, 1);
  sev = __shfl(sev, 0);
  float2 fv = ((const float2*)(f + (size_t)r * DDIM))[lane];
  float scf = inv_fT[r];
  float dt = fv.x * scf * (csum_i32[rc * DDIM + 2 * lane] * INV_CSC)
           + fv.y * scf * (csum_i32[rc * DDIM + 2 * lane + 1] * INV_CSC);
  #pragma unroll
  for (int m = 32; m; m >>= 1) dt += __shfl_xor(dt, m);
  if (lane == 0) {
    float L = logf(sev + 1e-12f);
    float C = (float)hist[rc] + C10;
    rowv[r] = (dt + S10 - C * L) / (C + 1e-12f);
  }
}

__global__ void final_kernel(const float* __restrict__ rowv, float* __restrict__ out) {
  __shared__ float sm[256];
  int t = threadIdx.x;
  float s = 0.f;
  for (int i = t; i < B_ROWS; i += 256) s += rowv[i];
  sm[t] = s;
  __syncthreads();
  for (int o = 128; o; o >>= 1) { if (t < o) sm[t] += sm[t + o]; __syncthreads(); }
  if (t == 0) out[0] = -(sm[0] / (float)B_ROWS);
}

extern "C" void kernel_launch(void* const* d_in, const int* in_sizes, int n_in,
                              void* d_out, int out_size, void* d_ws, size_t ws_size,
                              hipStream_t stream) {
  const float* f  = (const float*)d_in[0];
  const int*   fc = (const int*)  d_in[1];
  const float* g  = (const float*)d_in[2];
  const int*   gc = (const int*)  d_in[3];
  float* out = (float*)d_out;

  char* ws = (char*)d_ws;
  char*  wsf2    = ws;                          // 512 KB
  char*  wsg2    = ws + 524288;                 // 16 MB
  float* inv_fT  = (float*)(ws + 17301504);     // 8 KB
  float* inv_g   = (float*)(ws + 17309696);     // 256 KB
  float* p_se    = (float*)(ws + 17571840);     // 128 KB
  int*   csum_i32= (int*)  (ws + 17702912);     // 51.2 KB  ─┐ zeroed
  int*   hist    = (int*)  (ws + 17754112);     // 512 B      │
  int*   cnt     = (int*)  (ws + 17754624);     // 8 KB       │
  int*   flags   = (int*)  (ws + 17762816);     // 8 KB      ─┘ (68096 B)
  float* lv      = (float*)(ws + 17771008);     // 2 MB
  int*   li      = (int*)  (ws + 19868160);     // 2 MB
  float* rowv    = (float*)(ws + 21965312);     // 8 KB  (total ~21 MB)

  hipMemsetAsync(ws + 17702912, 0, 68096, stream);

  prep_kernel<<<(B_ROWS + N_GLB) / 4, 256, 0, stream>>>(f, g, wsf2, wsg2, inv_fT, inv_g);
  csum_kernel<<<128, 128, 0, stream>>>(g, gc, inv_g, csum_i32, hist);

  dim3 grid(NSPLIT, B_ROWS / 64);   // x=chunk (XCD locality), y=row-block
  sim_kernel<<<grid, 256, 0, stream>>>(wsf2, wsg2, p_se, lv, li, cnt);

  merge_kernel<<<B_ROWS / 4, 256, 0, stream>>>(f, fc, gc, inv_fT, p_se, csum_i32,
                                               hist, lv, li, cnt, flags, rowv);
  fallback_kernel<<<B_ROWS / 4, 256, 0, stream>>>(f, fc, gc, inv_fT, p_se, csum_i32,
                                                  hist, wsf2, wsg2, flags, rowv);
  final_kernel<<<1, 256, 0, stream>>>(rowv, out);
}